// Round 7
// baseline (218.288 us; speedup 1.0000x reference)
//
#include <hip/hip_runtime.h>

// SSIM 3D loss: pred/target f32 [4,1,64,192,192], scalar 1 - mean(ssim_map).
// v17: v16 + 4-WAY D-CHUNK SPLIT (occupancy fix). Grid was 1152 blocks =
//      4.5 blocks/CU = 18 waves/CU (56% cap, 30% measured) -> every latency
//      stall exposed. Now 16 outputs/chunk: planes 21/26/26/21 (+27% work)
//      but 2304 blocks = 9 blocks/CU -> residency-saturated (8/CU cap).
//      Ramp logic generalizes: q0=max(0,d_lo-5), q1=min(63,d_hi+5); the
//      q-5>=d_lo emit gate + d<=d_hi tail gate handle interior chunks.
//      Everything else identical to v16 (pk-f32, f32 SoA, BAR_LDS).

#define D_DIM 64
#define H_DIM 192
#define W_DIM 192
#define SLICE (H_DIM * W_DIM)   // 36864
#define VOL   (D_DIM * SLICE)   // 2359296
#define NB    4
#define KS    11
#define RAD   5
#define TIL   16                // output tile 16x16
#define HLO   26                // halo extent
#define SROWS 32                // padded stage rows (2 uniform W tasks/thread)
#define SP2   28                // f32x2 staging pitch
#define IPP   17                // interm pitch (elements) per row
#define NCH   4                 // D chunks
#define C1F   (0.01f * 0.01f)
#define C2F   (0.03f * 0.03f)

typedef float f32x2 __attribute__((ext_vector_type(2)));

// LDS-only barrier: order LDS ops, leave global loads (vmcnt) in flight.
#define BAR_LDS() do {                                                    \
    asm volatile("s_waitcnt lgkmcnt(0)" ::: "memory");                    \
    __builtin_amdgcn_s_barrier();                                         \
    __builtin_amdgcn_sched_barrier(0);                                    \
} while (0)

__device__ __forceinline__ void make_window(float* g) {
    float s = 0.f;
#pragma unroll
    for (int i = 0; i < KS; ++i) {
        float c = (float)(i - RAD);
        g[i] = expf(-(c * c) * (1.0f / 4.5f));  // 2*sigma^2 = 4.5
        s += g[i];
    }
    float inv = 1.0f / s;
#pragma unroll
    for (int i = 0; i < KS; ++i) g[i] *= inv;
}

#define SSIM_ACC(MP, MT, E2, T2, PT) do {                                 \
    float _mps = (MP) * (MP), _mts = (MT) * (MT), _mpt = (MP) * (MT);     \
    float _num = (2.f * _mpt + C1F) * (2.f * ((PT) - _mpt) + C2F);        \
    float _den = (_mps + _mts + C1F) *                                    \
                 (((E2) - _mps) + ((T2) - _mts) + C2F);                   \
    ssim_sum += _num * __builtin_amdgcn_rcpf(_den);                       \
} while (0)

__global__ __launch_bounds__(256) void fused_ssim_kernel(
    const float* __restrict__ pred, const float* __restrict__ targ,
    float* __restrict__ partials) {
    __shared__ f32x2 spt[SROWS * SP2];               // 7168 B
    __shared__ f32x2 i01[SROWS * IPP];               // 4352 B
    __shared__ f32x2 i23[SROWS * IPP];               // 4352 B
    __shared__ float i4 [SROWS * IPP];               // 2176 B
    __shared__ float red[4];

    float g[KS];
    make_window(g);

    const int tid = threadIdx.x;
    const int h0 = (blockIdx.x / 12) * TIL;
    const int w0 = (blockIdx.x % 12) * TIL;
    const int chunk = blockIdx.y;
    const float* pb = pred + (size_t)blockIdx.z * VOL;
    const float* tb = targ + (size_t)blockIdx.z * VOL;
    const int d_lo = chunk * (D_DIM / NCH);
    const int d_hi = d_lo + (D_DIM / NCH) - 1;
    const int q0 = (d_lo - RAD) > 0 ? (d_lo - RAD) : 0;
    const int q1 = (d_hi + RAD) < (D_DIM - 1) ? (d_hi + RAD) : (D_DIM - 1);

    // ---- zero pad rows 26..31 of stage (read by W, never written) ----
    for (int i = HLO * SP2 + tid; i < SROWS * SP2; i += 256)
        spt[i] = (f32x2){0.f, 0.f};
    // (visibility to W ordered by the loop's first barrier)

    // ---- plane-invariant staging precompute (676 halo px, 3 strides) ----
    int sidx[3], slds[3];
    bool sa[3], sv[3];
#pragma unroll
    for (int k = 0; k < 3; ++k) {
        int i = tid + 256 * k;
        sa[k] = i < HLO * HLO;
        int y = i / HLO, x = i - y * HLO;
        int gh = h0 + y - RAD, gw = w0 + x - RAD;
        sv[k] = sa[k] && (unsigned)gh < (unsigned)H_DIM &&
                (unsigned)gw < (unsigned)W_DIM;
        sidx[k] = gh * W_DIM + gw;
        slds[k] = y * SP2 + x;
    }
    const int py = tid >> 4, px = tid & 15;          // H-phase pixel

    // ---- D-window accumulators: slot j = output d = q + j - 5 ----
    f32x2 a01[KS], a23[KS];
    float a4[KS];
#pragma unroll
    for (int j = 0; j < KS; ++j) {
        a01[j] = (f32x2){0.f, 0.f};
        a23[j] = (f32x2){0.f, 0.f};
        a4[j] = 0.f;
    }
    float ssim_sum = 0.f;

    // prologue: load plane q0 into regs
    float rp[3], rt[3];
    {
        const float* pq = pb + q0 * SLICE;
        const float* tq = tb + q0 * SLICE;
#pragma unroll
        for (int k = 0; k < 3; ++k) {
            rp[k] = sv[k] ? pq[sidx[k]] : 0.f;
            rt[k] = sv[k] ? tq[sidx[k]] : 0.f;
        }
    }

    for (int q = q0;; ++q) {
        // commit staged regs -> LDS (vmcnt auto-wait lands here, one full
        // plane after issue; WAR vs W(q-1) ordered by barrier2(q-1))
#pragma unroll
        for (int k = 0; k < 3; ++k)
            if (sa[k]) spt[slds[k]] = (f32x2){rp[k], rt[k]};
        // prefetch next plane; stays in flight across both barriers
        if (q < q1) {
            const float* pn = pb + (q + 1) * SLICE;
            const float* tn = tb + (q + 1) * SLICE;
#pragma unroll
            for (int k = 0; k < 3; ++k) {
                rp[k] = sv[k] ? pn[sidx[k]] : 0.f;
                rt[k] = sv[k] ? tn[sidx[k]] : 0.f;
            }
        }
        BAR_LDS();                                   // stage visible; H(q-1) done

        // ---- W phase: 512 uniform tasks (32 rows x 16 cols), pk-f32 ----
#pragma unroll
        for (int it = 0; it < 2; ++it) {
            int t = tid + it * 256;                  // 0..511, all valid
            int r = t >> 4, c = t & 15;
            const f32x2* pr = spt + r * SP2 + c;
            f32x2 s01 = (f32x2){0.f, 0.f};
            f32x2 s23 = (f32x2){0.f, 0.f};
            float s4 = 0.f;
#pragma unroll
            for (int k = 0; k < KS; ++k) {
                f32x2 v = pr[k];                     // ds_read_b64
                float gk = g[k];
                f32x2 gk2 = (f32x2){gk, gk};
                s01 += gk2 * v;                      // v_pk_fma_f32
                s23 += gk2 * (v * v);                // v_pk_mul + v_pk_fma
                s4 += gk * (v.x * v.y);              // v_mul + v_fma
            }
            int oi = r * IPP + c;
            i01[oi] = s01;                           // ds_write_b64
            i23[oi] = s23;                           // ds_write_b64
            i4 [oi] = s4;                            // ds_write_b32
        }
        BAR_LDS();                                   // interm visible

        // ---- H phase (pk-f32) + D accumulate + emit ----
        {
            const f32x2* c01 = i01 + px;
            const f32x2* c23 = i23 + px;
            const float* c4  = i4  + px;
            f32x2 v01 = (f32x2){0.f, 0.f};
            f32x2 v23 = (f32x2){0.f, 0.f};
            float v4 = 0.f;
#pragma unroll
            for (int k = 0; k < KS; ++k) {
                int rr = (py + k) * IPP;
                float gk = g[k];
                f32x2 gk2 = (f32x2){gk, gk};
                v01 += gk2 * c01[rr];                // ds_read_b64 + pk_fma
                v23 += gk2 * c23[rr];                // ds_read_b64 + pk_fma
                v4 += gk * c4[rr];                   // ds_read_b32 + fma
            }
            // plane q contributes g[10-j] to output d = q + j - 5
#pragma unroll
            for (int j = 0; j < KS; ++j) {
                float wj = g[10 - j];
                f32x2 wj2 = (f32x2){wj, wj};
                a01[j] += wj2 * v01;
                a23[j] += wj2 * v23;
                a4[j] += wj * v4;
            }
            if (q - 5 >= d_lo)                       // d = q-5 complete
                SSIM_ACC(a01[0].x, a01[0].y, a23[0].x, a23[0].y, a4[0]);
            // shift window down (compile-time indices -> registers)
#pragma unroll
            for (int j = 0; j < KS - 1; ++j) {
                a01[j] = a01[j + 1]; a23[j] = a23[j + 1]; a4[j] = a4[j + 1];
            }
            a01[10] = (f32x2){0.f, 0.f};
            a23[10] = (f32x2){0.f, 0.f};
            a4[10] = 0.f;
        }
        if (q == q1) break;
    }

    // ---- tail: outputs d = q1-4 .. q1 (zero-padded D windows; only the
    //      last chunk passes the d<=d_hi gate, matching D-edge truncation) ----
#pragma unroll
    for (int j = 0; j < 5; ++j) {
        int d = q1 - 4 + j;
        if (d >= d_lo && d <= d_hi)
            SSIM_ACC(a01[j].x, a01[j].y, a23[j].x, a23[j].y, a4[j]);
    }

    // ---- block reduction ----
    float a = ssim_sum;
#pragma unroll
    for (int off = 32; off > 0; off >>= 1) a += __shfl_down(a, off, 64);
    int lane = tid & 63, wv = tid >> 6;
    if (lane == 0) red[wv] = a;
    __syncthreads();
    if (tid == 0)
        partials[((blockIdx.z * NCH + blockIdx.y) * 144) + blockIdx.x] =
            red[0] + red[1] + red[2] + red[3];
}

// ---- final reduction ----
__global__ __launch_bounds__(256) void finalize_kernel(
    const float* __restrict__ partials, int n, float* __restrict__ out) {
    double a = 0.0;
    for (int i = threadIdx.x; i < n; i += 256) a += (double)partials[i];
#pragma unroll
    for (int off = 32; off > 0; off >>= 1) a += __shfl_down(a, off, 64);
    __shared__ double red[4];
    int lane = threadIdx.x & 63, wv = threadIdx.x >> 6;
    if (lane == 0) red[wv] = a;
    __syncthreads();
    if (threadIdx.x == 0) {
        double s = red[0] + red[1] + red[2] + red[3];
        out[0] = (float)(1.0 - s / (double)((long long)NB * VOL));
    }
}

extern "C" void kernel_launch(void* const* d_in, const int* in_sizes, int n_in,
                              void* d_out, int out_size, void* d_ws, size_t ws_size,
                              hipStream_t stream) {
    const float* pred = (const float*)d_in[0];
    const float* targ = (const float*)d_in[1];
    float* out = (float*)d_out;
    float* partials = (float*)d_ws;                  // NB*576 floats

    fused_ssim_kernel<<<dim3(144, NCH, NB), 256, 0, stream>>>(pred, targ, partials);
    finalize_kernel<<<1, 256, 0, stream>>>(partials, NB * NCH * 144, out);
}

// Round 8
// 201.355 us; speedup vs baseline: 1.0841x; 1.0841x over previous
//
#include <hip/hip_runtime.h>

// SSIM 3D loss: pred/target f32 [4,1,64,192,192], scalar 1 - mean(ssim_map).
// v18: v16 (2-half, pk-f32, f32 SoA) + SINGLE-BARRIER 3-STAGE PIPELINE.
//      v16 was phase-locked: barriers force all resident waves into the same
//      phase, so LDS-pipe (~50%) and VALU (~51%) alternate instead of
//      overlapping. Double-buffer stage+interm; each iteration runs
//      commit(plane i) || W(plane i-1) || H+D(plane i-2) then ONE barrier.
//      Hazards: CM(i)->S[i&1] read by W(i+1) (1 barrier); W(i)->I[(i-1)&1]
//      read by H(i+1) (1 barrier); prior readers one barrier before (WAR ok);
//      intra-phase buffers disjoint. Barriers/plane 2 -> 1 (74 -> 39).
//      LDS 18.4 -> 36.1 KB -> 4 blocks/CU (grid is 4.5/CU).
//      v17's 4-chunk split REVERTED (+27% work for +12% efficiency).

#define D_DIM 64
#define H_DIM 192
#define W_DIM 192
#define SLICE (H_DIM * W_DIM)   // 36864
#define VOL   (D_DIM * SLICE)   // 2359296
#define NB    4
#define KS    11
#define RAD   5
#define TIL   16                // output tile 16x16
#define HLO   26                // halo extent
#define SROWS 32                // padded stage rows (2 uniform W tasks/thread)
#define SP2   28                // f32x2 staging pitch
#define IPP   17                // interm pitch (elements) per row
#define NPL   36                // q1 - q0, both halves
#define C1F   (0.01f * 0.01f)
#define C2F   (0.03f * 0.03f)

typedef float f32x2 __attribute__((ext_vector_type(2)));

// LDS-only barrier: order LDS ops, leave global loads (vmcnt) in flight.
#define BAR_LDS() do {                                                    \
    asm volatile("s_waitcnt lgkmcnt(0)" ::: "memory");                    \
    __builtin_amdgcn_s_barrier();                                         \
    __builtin_amdgcn_sched_barrier(0);                                    \
} while (0)

__device__ __forceinline__ void make_window(float* g) {
    float s = 0.f;
#pragma unroll
    for (int i = 0; i < KS; ++i) {
        float c = (float)(i - RAD);
        g[i] = expf(-(c * c) * (1.0f / 4.5f));  // 2*sigma^2 = 4.5
        s += g[i];
    }
    float inv = 1.0f / s;
#pragma unroll
    for (int i = 0; i < KS; ++i) g[i] *= inv;
}

#define SSIM_ACC(MP, MT, E2, T2, PT) do {                                 \
    float _mps = (MP) * (MP), _mts = (MT) * (MT), _mpt = (MP) * (MT);     \
    float _num = (2.f * _mpt + C1F) * (2.f * ((PT) - _mpt) + C2F);        \
    float _den = (_mps + _mts + C1F) *                                    \
                 (((E2) - _mps) + ((T2) - _mts) + C2F);                   \
    ssim_sum += _num * __builtin_amdgcn_rcpf(_den);                       \
} while (0)

// ---- pipeline phase macros (i = iteration index) ----
// commit plane q0+i from prefetch regs into S[i&1]
#define CM(i) do {                                                        \
    f32x2* _s = Sb[(i) & 1];                                              \
    _Pragma("unroll")                                                     \
    for (int _k = 0; _k < 3; ++_k)                                        \
        if (sa[_k]) _s[slds[_k]] = (f32x2){rp[_k], rt[_k]};               \
} while (0)

// prefetch plane q0+i+1 into regs (in flight across barriers)
#define PF(i) do {                                                        \
    const float* _pn = pb + (q0 + (i) + 1) * SLICE;                       \
    const float* _tn = tb + (q0 + (i) + 1) * SLICE;                       \
    _Pragma("unroll")                                                     \
    for (int _k = 0; _k < 3; ++_k) {                                      \
        rp[_k] = sv[_k] ? _pn[sidx[_k]] : 0.f;                            \
        rt[_k] = sv[_k] ? _tn[sidx[_k]] : 0.f;                            \
    }                                                                     \
} while (0)

// W-blur plane q0+i-1: read S[(i-1)&1] -> write I*[(i-1)&1]
#define WPH(i) do {                                                       \
    const int _b = ((i) - 1) & 1;                                         \
    const f32x2* _sp = Sb[_b];                                            \
    _Pragma("unroll")                                                     \
    for (int _it = 0; _it < 2; ++_it) {                                   \
        int _t = tid + _it * 256;                                         \
        int _r = _t >> 4, _c = _t & 15;                                   \
        const f32x2* _pr = _sp + _r * SP2 + _c;                           \
        f32x2 _s01 = (f32x2){0.f, 0.f};                                   \
        f32x2 _s23 = (f32x2){0.f, 0.f};                                   \
        float _s4 = 0.f;                                                  \
        _Pragma("unroll")                                                 \
        for (int _k = 0; _k < KS; ++_k) {                                 \
            f32x2 _v = _pr[_k];                                           \
            float _gk = g[_k];                                            \
            f32x2 _g2 = (f32x2){_gk, _gk};                                \
            _s01 += _g2 * _v;                                             \
            _s23 += _g2 * (_v * _v);                                      \
            _s4 += _gk * (_v.x * _v.y);                                   \
        }                                                                 \
        int _oi = _r * IPP + _c;                                          \
        I01b[_b][_oi] = _s01;                                             \
        I23b[_b][_oi] = _s23;                                             \
        I4b [_b][_oi] = _s4;                                              \
    }                                                                     \
} while (0)

// H-blur + D-accum + emit for plane q0+i-2: read I*[i&1]
#define HPH(i) do {                                                       \
    const int _b = (i) & 1;                                               \
    const f32x2* _c01 = I01b[_b] + px;                                    \
    const f32x2* _c23 = I23b[_b] + px;                                    \
    const float* _c4  = I4b [_b] + px;                                    \
    f32x2 _v01 = (f32x2){0.f, 0.f};                                       \
    f32x2 _v23 = (f32x2){0.f, 0.f};                                       \
    float _v4 = 0.f;                                                      \
    _Pragma("unroll")                                                     \
    for (int _k = 0; _k < KS; ++_k) {                                     \
        int _rr = (py + _k) * IPP;                                        \
        float _gk = g[_k];                                                \
        f32x2 _g2 = (f32x2){_gk, _gk};                                    \
        _v01 += _g2 * _c01[_rr];                                          \
        _v23 += _g2 * _c23[_rr];                                          \
        _v4 += _gk * _c4[_rr];                                            \
    }                                                                     \
    _Pragma("unroll")                                                     \
    for (int _j = 0; _j < KS; ++_j) {                                     \
        float _wj = g[10 - _j];                                           \
        f32x2 _w2 = (f32x2){_wj, _wj};                                    \
        a01[_j] += _w2 * _v01;                                            \
        a23[_j] += _w2 * _v23;                                            \
        a4[_j] += _wj * _v4;                                              \
    }                                                                     \
    if (q0 + (i) - 7 >= d_lo)                                             \
        SSIM_ACC(a01[0].x, a01[0].y, a23[0].x, a23[0].y, a4[0]);          \
    _Pragma("unroll")                                                     \
    for (int _j = 0; _j < KS - 1; ++_j) {                                 \
        a01[_j] = a01[_j + 1]; a23[_j] = a23[_j + 1]; a4[_j] = a4[_j + 1];\
    }                                                                     \
    a01[10] = (f32x2){0.f, 0.f};                                          \
    a23[10] = (f32x2){0.f, 0.f};                                          \
    a4[10] = 0.f;                                                         \
} while (0)

__global__ __launch_bounds__(256) void fused_ssim_kernel(
    const float* __restrict__ pred, const float* __restrict__ targ,
    float* __restrict__ partials) {
    __shared__ f32x2 Sb[2][SROWS * SP2];             // 14336 B
    __shared__ f32x2 I01b[2][SROWS * IPP];           // 8704 B
    __shared__ f32x2 I23b[2][SROWS * IPP];           // 8704 B
    __shared__ float I4b[2][SROWS * IPP];            // 4352 B
    __shared__ float red[4];

    float g[KS];
    make_window(g);

    const int tid = threadIdx.x;
    const int h0 = (blockIdx.x / 12) * TIL;
    const int w0 = (blockIdx.x % 12) * TIL;
    const int half = blockIdx.y;
    const float* pb = pred + (size_t)blockIdx.z * VOL;
    const float* tb = targ + (size_t)blockIdx.z * VOL;
    const int q0 = half ? 27 : 0;                    // first plane
    const int d_lo = half ? 32 : 0;
    const int d_hi = half ? 63 : 31;

    // ---- zero pad rows 26..31 of BOTH stage buffers (read, never written) --
    for (int i = HLO * SP2 + tid; i < SROWS * SP2; i += 256) {
        Sb[0][i] = (f32x2){0.f, 0.f};
        Sb[1][i] = (f32x2){0.f, 0.f};
    }
    // (visibility to W ordered by >=1 barrier before first W read)

    // ---- plane-invariant staging precompute (676 halo px, 3 strides) ----
    int sidx[3], slds[3];
    bool sa[3], sv[3];
#pragma unroll
    for (int k = 0; k < 3; ++k) {
        int i = tid + 256 * k;
        sa[k] = i < HLO * HLO;
        int y = i / HLO, x = i - y * HLO;
        int gh = h0 + y - RAD, gw = w0 + x - RAD;
        sv[k] = sa[k] && (unsigned)gh < (unsigned)H_DIM &&
                (unsigned)gw < (unsigned)W_DIM;
        sidx[k] = gh * W_DIM + gw;
        slds[k] = y * SP2 + x;
    }
    const int py = tid >> 4, px = tid & 15;          // H-phase pixel

    // ---- D-window accumulators: slot j = output d = p + j - 5 ----
    f32x2 a01[KS], a23[KS];
    float a4[KS];
#pragma unroll
    for (int j = 0; j < KS; ++j) {
        a01[j] = (f32x2){0.f, 0.f};
        a23[j] = (f32x2){0.f, 0.f};
        a4[j] = 0.f;
    }
    float ssim_sum = 0.f;

    // prologue: load plane q0 into regs
    float rp[3], rt[3];
    {
        const float* pq = pb + q0 * SLICE;
        const float* tq = tb + q0 * SLICE;
#pragma unroll
        for (int k = 0; k < 3; ++k) {
            rp[k] = sv[k] ? pq[sidx[k]] : 0.f;
            rt[k] = sv[k] ? tq[sidx[k]] : 0.f;
        }
    }

    // ---- pipeline: iter i runs CM(i) || W(i-1) || H(i-2), one barrier ----
    CM(0); PF(0); BAR_LDS();                         // i = 0
    CM(1); PF(1); WPH(1); BAR_LDS();                 // i = 1
    for (int i = 2; i <= NPL - 1; ++i) {             // i = 2..35 (uniform)
        CM(i); PF(i); WPH(i); HPH(i); BAR_LDS();
    }
    CM(NPL); WPH(NPL); HPH(NPL); BAR_LDS();          // i = 36 (no prefetch)
    WPH(NPL + 1); HPH(NPL + 1); BAR_LDS();           // i = 37 (no commit)
    HPH(NPL + 2);                                    // i = 38 (drain)

    // ---- tail: outputs d = q1-4 .. q1 (zero-padded D windows; the d<=d_hi
    //      gate makes half0 emit nothing, half1 emit d=59..63) ----
#pragma unroll
    for (int j = 0; j < 5; ++j) {
        int d = q0 + NPL - 4 + j;
        if (d >= d_lo && d <= d_hi)
            SSIM_ACC(a01[j].x, a01[j].y, a23[j].x, a23[j].y, a4[j]);
    }

    // ---- block reduction ----
    float a = ssim_sum;
#pragma unroll
    for (int off = 32; off > 0; off >>= 1) a += __shfl_down(a, off, 64);
    int lane = tid & 63, wv = tid >> 6;
    if (lane == 0) red[wv] = a;
    __syncthreads();
    if (tid == 0)
        partials[((blockIdx.z * 2 + blockIdx.y) * 144) + blockIdx.x] =
            red[0] + red[1] + red[2] + red[3];
}

// ---- final reduction ----
__global__ __launch_bounds__(256) void finalize_kernel(
    const float* __restrict__ partials, int n, float* __restrict__ out) {
    double a = 0.0;
    for (int i = threadIdx.x; i < n; i += 256) a += (double)partials[i];
#pragma unroll
    for (int off = 32; off > 0; off >>= 1) a += __shfl_down(a, off, 64);
    __shared__ double red[4];
    int lane = threadIdx.x & 63, wv = threadIdx.x >> 6;
    if (lane == 0) red[wv] = a;
    __syncthreads();
    if (threadIdx.x == 0) {
        double s = red[0] + red[1] + red[2] + red[3];
        out[0] = (float)(1.0 - s / (double)((long long)NB * VOL));
    }
}

extern "C" void kernel_launch(void* const* d_in, const int* in_sizes, int n_in,
                              void* d_out, int out_size, void* d_ws, size_t ws_size,
                              hipStream_t stream) {
    const float* pred = (const float*)d_in[0];
    const float* targ = (const float*)d_in[1];
    float* out = (float*)d_out;
    float* partials = (float*)d_ws;                  // NB*288 floats

    fused_ssim_kernel<<<dim3(144, 2, NB), 256, 0, stream>>>(pred, targ, partials);
    finalize_kernel<<<1, 256, 0, stream>>>(partials, NB * 288, out);
}